// Round 14
// baseline (765.400 us; speedup 1.0000x reference)
//
#include <hip/hip_runtime.h>
#include <stdint.h>

#define NE 131072

typedef __attribute__((ext_vector_type(8))) short bf16x8;
typedef __attribute__((ext_vector_type(4))) float f32x4;

static __device__ __forceinline__ unsigned short f2bf(float f) {
  unsigned u = __float_as_uint(f);
  u += 0x7FFF + ((u >> 16) & 1);   // round-to-nearest-even
  return (unsigned short)(u >> 16);
}
static __device__ __forceinline__ float bf2f(unsigned short h) {
  return __uint_as_float((unsigned)h << 16);
}
static __device__ __forceinline__ void gload_lds16(const void* g, void* l) {
  __builtin_amdgcn_global_load_lds(
      (const __attribute__((address_space(1))) unsigned*)g,
      (__attribute__((address_space(3))) unsigned*)l, 16, 0, 0);
}

// Fused weight prep (verified R4-R13): dst[n][k] = bf16(src[k][n])
__global__ void weight_prep(const float* __restrict__ W0, const float* __restrict__ W1,
                            const float* __restrict__ W2, const float* __restrict__ SW0,
                            const float* __restrict__ SW1, const float* __restrict__ SW2,
                            unsigned short* W0t, unsigned short* W1t,
                            unsigned short* W2t, unsigned short* SW0t,
                            unsigned short* SW1t, unsigned short* SW2b) {
  __shared__ float tile[32][33];
  const int u = blockIdx.y;
  const float* src; unsigned short* dst; int K, Nc;
  if (u == 0)      { src = W0;  dst = W0t;  K = 64;  Nc = 512; }
  else if (u == 1) { src = W1;  dst = W1t;  K = 512; Nc = 512; }
  else if (u == 2) { src = W2;  dst = W2t;  K = 512; Nc = 512; }
  else if (u < 6)  { int p = u - 3; src = SW0 + (long)p * 512 * 512; dst = SW0t + (long)p * 512 * 512; K = 512; Nc = 512; }
  else if (u < 9)  { int p = u - 6; src = SW1 + (long)p * 512 * 256; dst = SW1t + (long)p * 256 * 512; K = 512; Nc = 256; }
  else             { int p = u - 9; src = SW2 + (long)p * 256;       dst = SW2b + (long)p * 256;       K = 256; Nc = 1; }
  const int tkn = K >> 5;
  const int tk = blockIdx.x % tkn, tn = blockIdx.x / tkn;
  if (tn >= ((Nc + 31) >> 5)) return;
  const int k0 = tk * 32, n0 = tn * 32;
  const int tx = threadIdx.x & 31, ty = threadIdx.x >> 5;
  if (n0 + tx < Nc)
#pragma unroll
    for (int j = 0; j < 4; ++j)
      tile[ty * 4 + j][tx] = src[(long)(k0 + ty * 4 + j) * Nc + n0 + tx];
  __syncthreads();
#pragma unroll
  for (int j = 0; j < 4; ++j) {
    int n = n0 + ty * 4 + j;
    if (n < Nc) dst[(long)n * K + k0 + tx] = f2bf(tile[tx][ty * 4 + j]);
  }
}

__global__ void relu_cvt_x(const float4* __restrict__ x,
                           ushort4* __restrict__ xb) {
  int i = blockIdx.x * blockDim.x + threadIdx.x;
  float4 v = x[i];
  ushort4 o;
  o.x = f2bf(fmaxf(v.x, 0.f));
  o.y = f2bf(fmaxf(v.y, 0.f));
  o.z = f2bf(fmaxf(v.z, 0.f));
  o.w = f2bf(fmaxf(v.w, 0.f));
  xb[i] = o;
}

// ---------------------------------------------------------------------------
// Persistent fused MLP. One block = 64 events end-to-end.
// LDS 160 KB: B-ring 3 x 32 KB at [0, 96 KB); actA 64 KB at [96 KB, 160 KB)
// as 16 panels of the R9-verified [64 rows][32 k] involution layout
// (byte = panel*4096 + row*64 + slot*16; chunk g stored at slot
//  g ^ ((row>>1)&3); reads use axr = (lh ^ ((lr>>1)&3)) — measured 0
//  bank conflicts in R6-R13). K-loop = R9's 3-ring counted-vmcnt schedule.
// ---------------------------------------------------------------------------

// Stage [64][K] bf16 global rows into actA panels (K = 64 or 512).
static __device__ __forceinline__ void restageA(
    uint8_t* lds, const unsigned short* __restrict__ src, int K,
    int wave, int lane) {
  unsigned short* actA = (unsigned short*)(lds + 98304);
  const int per = (K == 64) ? 1 : 8;      // 512 or 4096 chunks / 512 threads
  for (int i = 0; i < per; ++i) {
    const int cb = i * 512 + wave * 64;   // wave-uniform chunk base
    const int c = cb + lane;
    const int panel = c >> 8, w = c & 255;
    const int row = w >> 2, sl = w & 3;
    const int kc = sl ^ ((row >> 1) & 3);
    gload_lds16(src + (long)row * K + panel * 32 + kc * 8, &actA[cb * 8]);
  }
  asm volatile("s_waitcnt vmcnt(0)" ::: "memory");
  __builtin_amdgcn_s_barrier();
}

// One GEMM layer: C[64][NT*128] += actA[64][K] x Bt[NT*128][K]^T.
// 8 waves, wave n-slice = NT*16 cols; acc[4][NT]. R9 ring schedule.
template <int NT>
static __device__ __forceinline__ void gemm_layer(
    uint8_t* lds, const unsigned short* __restrict__ Bt, int K,
    f32x4 (&acc)[4][NT], int wave, int lane, int lr, int lh, int axr) {
  const int nk = K >> 5;
  const unsigned short* actA = (const unsigned short*)(lds + 98304);
  auto STAGE = [&](int t) {
    if (t >= nk) return;
    unsigned short* dst = (unsigned short*)(lds + (t % 3) * 32768);
    const int k0 = t << 5;
#pragma unroll
    for (int i = 0; i < NT; ++i) {
      const int cb = i * 512 + wave * 64;
      const int c = cb + lane;
      const int r = c >> 2;
      const int kc = (c & 3) ^ ((r >> 1) & 3);
      gload_lds16(Bt + (long)r * K + k0 + kc * 8, &dst[cb * 8]);
    }
  };
  STAGE(0);
  STAGE(1);
  for (int t = 0; t < nk; ++t) {
    if (t < nk - 1) {
      if constexpr (NT == 4)
        asm volatile("s_waitcnt vmcnt(4)" ::: "memory");
      else
        asm volatile("s_waitcnt vmcnt(2)" ::: "memory");
    } else {
      asm volatile("s_waitcnt vmcnt(0)" ::: "memory");
    }
    __builtin_amdgcn_s_barrier();
    __builtin_amdgcn_sched_barrier(0);
    const unsigned short* buf = (const unsigned short*)(lds + (t % 3) * 32768);
    bf16x8 a[4], b[NT];
#pragma unroll
    for (int m = 0; m < 4; ++m)
      a[m] = *(const bf16x8*)&actA[t * 2048 + (m * 16 + lr) * 32 + axr];
#pragma unroll
    for (int n = 0; n < NT; ++n)
      b[n] = *(const bf16x8*)&buf[(wave * (NT * 16) + n * 16 + lr) * 32 + axr];
    STAGE(t + 2);
    __builtin_amdgcn_s_setprio(1);
#pragma unroll
    for (int m = 0; m < 4; ++m)
#pragma unroll
      for (int n = 0; n < NT; ++n)
        acc[m][n] =
            __builtin_amdgcn_mfma_f32_16x16x32_bf16(a[m], b[n], acc[m][n], 0, 0, 0);
    __builtin_amdgcn_s_setprio(0);
  }
}

// Epilogue: v = acc + bias; write bf16(relu(v)) back into actA (in place,
// involution layout); optionally also v -> outRe (fp32) and relu -> bufR.
static __device__ __forceinline__ void epi_actA(
    uint8_t* lds, f32x4 (&acc)[4][4], const float* __restrict__ bias,
    int wave, int lr, int lh, bool toGlobal,
    float* __restrict__ outRe, unsigned short* __restrict__ bufRg, long band0) {
  unsigned short* actA = (unsigned short*)(lds + 98304);
  float bv[4];
#pragma unroll
  for (int n = 0; n < 4; ++n) bv[n] = bias[wave * 64 + n * 16 + lr];
  __builtin_amdgcn_s_barrier();            // all waves done reading old actA
#pragma unroll
  for (int m = 0; m < 4; ++m)
#pragma unroll
    for (int n = 0; n < 4; ++n) {
      const int feat = wave * 64 + n * 16 + lr;
      const int panel = feat >> 5, c2 = (feat >> 3) & 3, f7 = feat & 7;
#pragma unroll
      for (int r = 0; r < 4; ++r) {
        const int event = m * 16 + lh * 4 + r;
        const float v = acc[m][n][r] + bv[n];
        const float rv = fmaxf(v, 0.f);
        const int slot = c2 ^ ((event >> 1) & 3);
        actA[panel * 2048 + event * 32 + slot * 8 + f7] = f2bf(rv);
        if (toGlobal) {
          outRe[(band0 + event) * 512 + feat] = v;
          bufRg[(band0 + event) * 512 + feat] = f2bf(rv);
        }
      }
    }
  asm volatile("s_waitcnt lgkmcnt(0)" ::: "memory");
  __builtin_amdgcn_s_barrier();            // actA ready for next layer
}

__global__ __launch_bounds__(512, 1) void fused_mlp(
    const unsigned short* __restrict__ Xb,
    const int* __restrict__ y, const int* __restrict__ pairs,
    const unsigned short* __restrict__ W0t, const float* __restrict__ b0,
    const unsigned short* __restrict__ W1t, const float* __restrict__ b1,
    const unsigned short* __restrict__ W2t, const float* __restrict__ b2,
    const unsigned short* __restrict__ SW0t, const float* __restrict__ Sb0,
    const unsigned short* __restrict__ SW1t, const float* __restrict__ Sb1,
    const unsigned short* __restrict__ SW2b, const float* __restrict__ Sb2,
    unsigned short* __restrict__ bufR,
    float* __restrict__ outRe, float* __restrict__ outR,
    float* __restrict__ outS, float* __restrict__ outM) {
  __shared__ uint8_t lds[163840];
  const int tid = threadIdx.x, wave = tid >> 6, lane = tid & 63;
  const int lr = lane & 15, lh = lane >> 4;
  const int axr = (lh ^ ((lr >> 1) & 3)) * 8;
  const long band0 = (long)blockIdx.x * 64;

  f32x4 acc4[4][4];
  auto zero4 = [&] {
#pragma unroll
    for (int m = 0; m < 4; ++m)
#pragma unroll
      for (int n = 0; n < 4; ++n) acc4[m][n] = (f32x4){0.f, 0.f, 0.f, 0.f};
  };

  // trunk
  restageA(lds, Xb + band0 * 64, 64, wave, lane);
  zero4();
  gemm_layer<4>(lds, W0t, 64, acc4, wave, lane, lr, lh, axr);
  epi_actA(lds, acc4, b0, wave, lr, lh, false, nullptr, nullptr, band0);
  zero4();
  gemm_layer<4>(lds, W1t, 512, acc4, wave, lane, lr, lh, axr);
  epi_actA(lds, acc4, b1, wave, lr, lh, false, nullptr, nullptr, band0);
  zero4();
  gemm_layer<4>(lds, W2t, 512, acc4, wave, lane, lr, lh, axr);
  epi_actA(lds, acc4, b2, wave, lr, lh, true, outRe, bufR, band0);

  // per-pair subnets
  for (int p = 0; p < 3; ++p) {
    if (p) restageA(lds, bufR + band0 * 512, 512, wave, lane);
    zero4();
    gemm_layer<4>(lds, SW0t + (long)p * 512 * 512, 512, acc4, wave, lane, lr,
                  lh, axr);
    epi_actA(lds, acc4, Sb0 + p * 512, wave, lr, lh, false, nullptr, nullptr,
             band0);
    f32x4 acc2[4][2];
#pragma unroll
    for (int m = 0; m < 4; ++m)
#pragma unroll
      for (int n = 0; n < 2; ++n) acc2[m][n] = (f32x4){0.f, 0.f, 0.f, 0.f};
    gemm_layer<2>(lds, SW1t + (long)p * 256 * 512, 512, acc2, wave, lane, lr,
                  lh, axr);
    // fused head: logit = sum relu(h1+b)*w2 + sb2; sigmoid/clip/ratio/mask
    float bv[2], wv[2];
#pragma unroll
    for (int n = 0; n < 2; ++n) {
      const int oc = wave * 32 + n * 16 + lr;
      bv[n] = Sb1[p * 256 + oc];
      wv[n] = bf2f(SW2b[p * 256 + oc]);
    }
    __builtin_amdgcn_s_barrier();          // ring buf0 free; SW1 reads done
    float* part = (float*)lds;             // [8][64] aliases ring buf0
#pragma unroll
    for (int m = 0; m < 4; ++m)
#pragma unroll
      for (int r = 0; r < 4; ++r) {
        float s = 0.f;
#pragma unroll
        for (int n = 0; n < 2; ++n)
          s += fmaxf(acc2[m][n][r] + bv[n], 0.f) * wv[n];
#pragma unroll
        for (int off = 1; off < 16; off <<= 1) s += __shfl_xor(s, off);
        if (lr == 0) part[wave * 64 + m * 16 + lh * 4 + r] = s;
      }
    __syncthreads();
    if (tid < 64) {
      float logit = Sb2[p];
#pragma unroll
      for (int w = 0; w < 8; ++w) logit += part[w * 64 + tid];
      float s = 1.f / (1.f + expf(-logit));
      s = fmaxf(s, 1e-9f);
      float rr = (1.f - s) / s;
      const int yv = y[band0 + tid];
      const float mf =
          (yv == pairs[p * 2] || yv == pairs[p * 2 + 1]) ? 1.f : 0.f;
      outR[(long)p * NE + band0 + tid] = rr * mf;
      outS[(long)p * NE + band0 + tid] = s * mf;
      outM[(long)p * NE + band0 + tid] = mf;
    }
    __syncthreads();                       // part read before next p's STAGE
  }
}

extern "C" void kernel_launch(void* const* d_in, const int* in_sizes, int n_in,
                              void* d_out, int out_size, void* d_ws, size_t ws_size,
                              hipStream_t stream) {
  const float* x   = (const float*)d_in[0];
  const int*   y   = (const int*)d_in[1];
  const int*   prs = (const int*)d_in[2];
  const float* W0  = (const float*)d_in[3];
  const float* b0  = (const float*)d_in[4];
  const float* W1  = (const float*)d_in[5];
  const float* b1  = (const float*)d_in[6];
  const float* W2  = (const float*)d_in[7];
  const float* b2  = (const float*)d_in[8];
  const float* SW0 = (const float*)d_in[9];
  const float* Sb0 = (const float*)d_in[10];
  const float* SW1 = (const float*)d_in[11];
  const float* Sb1 = (const float*)d_in[12];
  const float* SW2 = (const float*)d_in[13];
  const float* Sb2 = (const float*)d_in[14];

  uint8_t* ws = (uint8_t*)d_ws;
  size_t off = 0;
  auto take = [&](size_t bytes) -> void* {
    void* ptr = ws + off;
    off = (off + bytes + 255) & ~(size_t)255;
    return ptr;
  };
  unsigned short* W0t  = (unsigned short*)take((size_t)64 * 512 * 2);
  unsigned short* W1t  = (unsigned short*)take((size_t)512 * 512 * 2);
  unsigned short* W2t  = (unsigned short*)take((size_t)512 * 512 * 2);
  unsigned short* SW0t = (unsigned short*)take((size_t)3 * 512 * 512 * 2);
  unsigned short* SW1t = (unsigned short*)take((size_t)3 * 256 * 512 * 2);
  unsigned short* SW2b = (unsigned short*)take((size_t)3 * 256 * 2);
  unsigned short* Xb   = (unsigned short*)take((size_t)NE * 64 * 2);
  unsigned short* bufR = (unsigned short*)take((size_t)NE * 512 * 2);

  float* out   = (float*)d_out;
  float* outRe = out;
  float* outR  = out + (size_t)NE * 512;
  float* outS  = outR + (size_t)3 * NE;
  float* outM  = outS + (size_t)3 * NE;

  weight_prep<<<dim3(256, 12), 256, 0, stream>>>(W0, W1, W2, SW0, SW1, SW2,
                                                 W0t, W1t, W2t, SW0t, SW1t, SW2b);
  relu_cvt_x<<<dim3(NE * 64 / 4 / 256), 256, 0, stream>>>((const float4*)x,
                                                          (ushort4*)Xb);
  fused_mlp<<<dim3(NE / 64), 512, 0, stream>>>(
      Xb, y, prs, W0t, b0, W1t, b1, W2t, b2, SW0t, Sb0, SW1t, Sb1, SW2b, Sb2,
      bufR, outRe, outR, outS, outM);
}

// Round 15
// 754.282 us; speedup vs baseline: 1.0147x; 1.0147x over previous
//
#include <hip/hip_runtime.h>
#include <stdint.h>

#define NE 131072

typedef __attribute__((ext_vector_type(8))) short bf16x8;
typedef __attribute__((ext_vector_type(4))) float f32x4;

static __device__ __forceinline__ unsigned short f2bf(float f) {
  unsigned u = __float_as_uint(f);
  u += 0x7FFF + ((u >> 16) & 1);   // round-to-nearest-even
  return (unsigned short)(u >> 16);
}
static __device__ __forceinline__ float bf2f(unsigned short h) {
  return __uint_as_float((unsigned)h << 16);
}
static __device__ __forceinline__ void gload_lds16(const void* g, void* l) {
  __builtin_amdgcn_global_load_lds(
      (const __attribute__((address_space(1))) unsigned*)g,
      (__attribute__((address_space(3))) unsigned*)l, 16, 0, 0);
}

// Fused weight prep (verified R4-R13): dst[n][k] = bf16(src[k][n])
__global__ void weight_prep(const float* __restrict__ W0, const float* __restrict__ W1,
                            const float* __restrict__ W2, const float* __restrict__ SW0,
                            const float* __restrict__ SW1, const float* __restrict__ SW2,
                            unsigned short* W0t, unsigned short* W1t,
                            unsigned short* W2t, unsigned short* SW0t,
                            unsigned short* SW1t, unsigned short* SW2b) {
  __shared__ float tile[32][33];
  const int u = blockIdx.y;
  const float* src; unsigned short* dst; int K, Nc;
  if (u == 0)      { src = W0;  dst = W0t;  K = 64;  Nc = 512; }
  else if (u == 1) { src = W1;  dst = W1t;  K = 512; Nc = 512; }
  else if (u == 2) { src = W2;  dst = W2t;  K = 512; Nc = 512; }
  else if (u < 6)  { int p = u - 3; src = SW0 + (long)p * 512 * 512; dst = SW0t + (long)p * 512 * 512; K = 512; Nc = 512; }
  else if (u < 9)  { int p = u - 6; src = SW1 + (long)p * 512 * 256; dst = SW1t + (long)p * 256 * 512; K = 512; Nc = 256; }
  else             { int p = u - 9; src = SW2 + (long)p * 256;       dst = SW2b + (long)p * 256;       K = 256; Nc = 1; }
  const int tkn = K >> 5;
  const int tk = blockIdx.x % tkn, tn = blockIdx.x / tkn;
  if (tn >= ((Nc + 31) >> 5)) return;
  const int k0 = tk * 32, n0 = tn * 32;
  const int tx = threadIdx.x & 31, ty = threadIdx.x >> 5;
  if (n0 + tx < Nc)
#pragma unroll
    for (int j = 0; j < 4; ++j)
      tile[ty * 4 + j][tx] = src[(long)(k0 + ty * 4 + j) * Nc + n0 + tx];
  __syncthreads();
#pragma unroll
  for (int j = 0; j < 4; ++j) {
    int n = n0 + ty * 4 + j;
    if (n < Nc) dst[(long)n * K + k0 + tx] = f2bf(tile[tx][ty * 4 + j]);
  }
}

__global__ void relu_cvt_x(const float4* __restrict__ x,
                           ushort4* __restrict__ xb) {
  int i = blockIdx.x * blockDim.x + threadIdx.x;
  float4 v = x[i];
  ushort4 o;
  o.x = f2bf(fmaxf(v.x, 0.f));
  o.y = f2bf(fmaxf(v.y, 0.f));
  o.z = f2bf(fmaxf(v.z, 0.f));
  o.w = f2bf(fmaxf(v.w, 0.f));
  xb[i] = o;
}

// Deterministic per-(chunk, pair) compaction (verified R12/R13).
__global__ void build_idx(const int* __restrict__ y, const int* __restrict__ pairs,
                          int chunkRows, int* __restrict__ idxL,
                          int* __restrict__ posA, int* __restrict__ cnts) {
  const int c = blockIdx.x, p = blockIdx.y;
  const int la = pairs[p * 2], lb = pairs[p * 2 + 1];
  const long r0 = (long)c * chunkRows;
  const long cb = r0;
  __shared__ int wbase[4];
  __shared__ int running;
  if (threadIdx.x == 0) running = 0;
  __syncthreads();
  const int lane = threadIdx.x & 63, wv = threadIdx.x >> 6;
  for (int it = 0; it < chunkRows / 256; ++it) {
    const int r = it * 256 + threadIdx.x;
    const int yv = y[r0 + r];
    const bool act = (yv == la) || (yv == lb);
    const unsigned long long m = __ballot(act);
    const int rank = __popcll(m & ((1ull << lane) - 1));
    if (lane == 0) wbase[wv] = __popcll(m);
    __syncthreads();
    int wb = 0;
#pragma unroll
    for (int w = 0; w < 4; ++w) wb += (w < wv) ? wbase[w] : 0;
    const int tot = wbase[0] + wbase[1] + wbase[2] + wbase[3];
    if (act) {
      const int posi = running + wb + rank;
      idxL[(long)p * NE + cb + posi] = r;
      posA[(long)p * NE + r0 + r] = (int)(cb + posi);
    } else {
      posA[(long)p * NE + r0 + r] = -1;
    }
    __syncthreads();
    if (threadIdx.x == 0) running += tot;
    __syncthreads();
  }
  const int cnt = running;
  if (threadIdx.x == 0) cnts[c * 3 + p] = cnt;
  const int padded = (cnt + 255) & ~255;
  const int last = (cnt > 0) ? idxL[(long)p * NE + cb + cnt - 1] : 0;
  for (int i = cnt + threadIdx.x; i < padded; i += 256)
    idxL[(long)p * NE + cb + i] = last;
}

// gemmT (R13-verified best): R9 schedule (3-ring 72KB, 2 blk/CU, counted
// vmcnt(3), involution addressing 0-conflict) with BM=128 x BN=256 geometry:
// 8 waves 2M x 4N -> 64x64 wave-tile (8 ds_read_b128 per 16 MFMA).
// Optional A-row gather (aIdx, K-invariant, hoisted) + early-exit (cnts).
// Optional fused full head (w2): Nc=256 fits one block -> complete logit.
__global__ __launch_bounds__(512, 4) void gemmT(
    const unsigned short* __restrict__ A, long aZ,
    const unsigned short* __restrict__ Bt, long bZ,
    const float* __restrict__ bias, long biasZ,
    float* __restrict__ outF,
    unsigned short* __restrict__ outA, long cZ,
    int K, int Nc,
    const unsigned short* __restrict__ w2, long w2Z,
    float* __restrict__ PB, long pbZ, int r0,
    const int* __restrict__ aIdx, long aIdxZ,
    const int* __restrict__ cnts) {
  __shared__ unsigned short lds[3 * 12288];   // 72 KB: per buf A 8KB + B 16KB
  __shared__ float part[4][128];
  const int z = blockIdx.z;
  const long brow = (long)blockIdx.x * 128;
  if (cnts) {
    const int cp = cnts[z];
    if ((int)brow >= ((cp + 255) & ~255)) return;
  }
  A += (long)z * aZ;
  Bt += (long)z * bZ;
  bias += (long)z * biasZ;
  if (outA) outA += (long)z * cZ;
  if (w2) { w2 += (long)z * w2Z; PB += (long)z * pbZ; }
  if (aIdx) aIdx += (long)z * aIdxZ;

  const int tid = threadIdx.x, wave = tid >> 6, lane = tid & 63;
  const int wm = wave >> 2, wn = wave & 3;   // 2M x 4N
  const int lr = lane & 15, lh = lane >> 4;
  const int bcol = blockIdx.y * 256;
  const int nk = K >> 5;
  const int axr = (lh ^ ((lr >> 1) & 3)) * 8;   // involution read col (elems)

  // A source row (K-tile-invariant; 1 stage-load/thread)
  const int arL = tid >> 2;                     // LDS-local A row 0..127
  const int arow = aIdx ? aIdx[brow + arL] : (int)(brow + arL);

  f32x4 acc[4][4];
#pragma unroll
  for (int m = 0; m < 4; ++m)
#pragma unroll
    for (int n = 0; n < 4; ++n) acc[m][n] = (f32x4){0.f, 0.f, 0.f, 0.f};

  auto STAGE = [&](int t) {
    if (t >= nk) return;
    unsigned short* dst = &lds[(t % 3) * 12288];
    const int k0 = t << 5;
    {                                           // A: 512 chunks, 1/thread
      const int c = tid;
      const int r = c >> 2;
      const int kc = (c & 3) ^ ((r >> 1) & 3);
      gload_lds16(A + (long)arow * K + k0 + kc * 8, &dst[(wave * 64) * 8]);
    }
#pragma unroll
    for (int i = 0; i < 2; ++i) {               // B: 1024 chunks, 2/thread
      const int cb = i * 512 + wave * 64;
      const int c = cb + lane;
      const int r = c >> 2;
      const int kc = (c & 3) ^ ((r >> 1) & 3);
      gload_lds16(Bt + (long)(bcol + r) * K + k0 + kc * 8,
                  &dst[(512 + cb) * 8]);
    }
  };

  STAGE(0);
  STAGE(1);

  for (int t = 0; t < nk; ++t) {
    if (t < nk - 1)
      asm volatile("s_waitcnt vmcnt(3)" ::: "memory");
    else
      asm volatile("s_waitcnt vmcnt(0)" ::: "memory");
    __builtin_amdgcn_s_barrier();
    __builtin_amdgcn_sched_barrier(0);
    const unsigned short* buf = &lds[(t % 3) * 12288];
    bf16x8 a[4], b[4];
#pragma unroll
    for (int m = 0; m < 4; ++m)
      a[m] = *(const bf16x8*)&buf[(wm * 64 + m * 16 + lr) * 32 + axr];
#pragma unroll
    for (int n = 0; n < 4; ++n)
      b[n] = *(const bf16x8*)&buf[512 * 8 + (wn * 64 + n * 16 + lr) * 32 + axr];
    STAGE(t + 2);
    __builtin_amdgcn_s_setprio(1);
#pragma unroll
    for (int m = 0; m < 4; ++m)
#pragma unroll
      for (int n = 0; n < 4; ++n)
        acc[m][n] =
            __builtin_amdgcn_mfma_f32_16x16x32_bf16(a[m], b[n], acc[m][n], 0, 0, 0);
    __builtin_amdgcn_s_setprio(0);
  }

  float bv[4];
#pragma unroll
  for (int n = 0; n < 4; ++n) bv[n] = bias[bcol + wn * 64 + n * 16 + lr];

  if (!w2) {
#pragma unroll
    for (int m = 0; m < 4; ++m) {
#pragma unroll
      for (int r = 0; r < 4; ++r) {
        long e = brow + wm * 64 + m * 16 + lh * 4 + r;
#pragma unroll
        for (int n = 0; n < 4; ++n) {
          int oc = bcol + wn * 64 + n * 16 + lr;
          float v = acc[m][n][r] + bv[n];
          if (outF) outF[e * Nc + oc] = v;
          if (outA) outA[e * Nc + oc] = f2bf(fmaxf(v, 0.f));
        }
      }
    }
  } else {
    // full fused head (Nc=256 in one block): logit partials per wn group
    float w2v[4];
#pragma unroll
    for (int n = 0; n < 4; ++n) w2v[n] = bf2f(w2[wn * 64 + n * 16 + lr]);
#pragma unroll
    for (int m = 0; m < 4; ++m) {
#pragma unroll
      for (int r = 0; r < 4; ++r) {
        float s = 0.f;
#pragma unroll
        for (int n = 0; n < 4; ++n)
          s += fmaxf(acc[m][n][r] + bv[n], 0.f) * w2v[n];
#pragma unroll
        for (int off = 1; off < 16; off <<= 1) s += __shfl_xor(s, off);
        if (lr == 0) part[wn][wm * 64 + m * 16 + lh * 4 + r] = s;
      }
    }
    __syncthreads();
    if (tid < 128)
      PB[r0 + brow + tid] =
          part[0][tid] + part[1][tid] + part[2][tid] + part[3][tid];
  }
}

// Scatter head: compact PB -> dense outputs via posA; zeros for masked.
__global__ void head_final(const float* __restrict__ PB,
                           const int* __restrict__ posA,
                           const float* __restrict__ Sb2,
                           float* __restrict__ outR, float* __restrict__ outS,
                           float* __restrict__ outM) {
  const long n = (long)blockIdx.x * 256 + threadIdx.x;
  const int p = blockIdx.y;
  const int pos = posA[(long)p * NE + n];
  float rr = 0.f, s = 0.f, mf = 0.f;
  if (pos >= 0) {
    float logit = PB[(long)p * NE + pos] + Sb2[p];
    s = 1.f / (1.f + expf(-logit));
    s = fmaxf(s, 1e-9f);
    rr = (1.f - s) / s;
    mf = 1.f;
  }
  outR[(long)p * NE + n] = rr;
  outS[(long)p * NE + n] = s;
  outM[(long)p * NE + n] = mf;
}

extern "C" void kernel_launch(void* const* d_in, const int* in_sizes, int n_in,
                              void* d_out, int out_size, void* d_ws, size_t ws_size,
                              hipStream_t stream) {
  const float* x   = (const float*)d_in[0];
  const int*   y   = (const int*)d_in[1];
  const int*   prs = (const int*)d_in[2];
  const float* W0  = (const float*)d_in[3];
  const float* b0  = (const float*)d_in[4];
  const float* W1  = (const float*)d_in[5];
  const float* b1  = (const float*)d_in[6];
  const float* W2  = (const float*)d_in[7];
  const float* b2  = (const float*)d_in[8];
  const float* SW0 = (const float*)d_in[9];
  const float* Sb0 = (const float*)d_in[10];
  const float* SW1 = (const float*)d_in[11];
  const float* Sb1 = (const float*)d_in[12];
  const float* SW2 = (const float*)d_in[13];
  const float* Sb2 = (const float*)d_in[14];

  uint8_t* ws = (uint8_t*)d_ws;
  size_t off = 0;
  auto take = [&](size_t bytes) -> void* {
    void* ptr = ws + off;
    off = (off + bytes + 255) & ~(size_t)255;
    return ptr;
  };
  unsigned short* W0t  = (unsigned short*)take((size_t)64 * 512 * 2);
  unsigned short* W1t  = (unsigned short*)take((size_t)512 * 512 * 2);
  unsigned short* W2t  = (unsigned short*)take((size_t)512 * 512 * 2);
  unsigned short* SW0t = (unsigned short*)take((size_t)3 * 512 * 512 * 2);
  unsigned short* SW1t = (unsigned short*)take((size_t)3 * 256 * 512 * 2);
  unsigned short* SW2b = (unsigned short*)take((size_t)3 * 256 * 2);
  unsigned short* Xb   = (unsigned short*)take((size_t)NE * 64 * 2);
  float*          PB   = (float*)take((size_t)3 * NE * 4);
  int*            idxL = (int*)take((size_t)3 * NE * 4);
  int*            posA = (int*)take((size_t)3 * NE * 4);
  int*            cnts = (int*)take((size_t)64 * 4);
  const size_t fixed = off;

  // Chunk 65536: halves the dependent-dispatch count vs 32768 (20 -> 10
  // serialization boundaries). L3 check: live producer->consumer pairs are
  // T0+T1 = 134 MB and bufR + compact-H3 ~ 200 MB, both < 256 MB Infinity
  // Cache (R6's thrash was 268+ MB live pairs at chunk=NE).
  long chunk = 65536;
  while (chunk > 8192 && fixed + (size_t)6 * chunk * 1024 + 4096 > ws_size)
    chunk >>= 1;
  const int nchunks = (int)(NE / chunk);

  unsigned short* T0   = (unsigned short*)take((size_t)chunk * 512 * 2);
  unsigned short* T1   = (unsigned short*)take((size_t)chunk * 512 * 2);
  unsigned short* bufR = (unsigned short*)take((size_t)chunk * 512 * 2);
  unsigned short* H3   = (unsigned short*)take((size_t)3 * chunk * 512 * 2);

  float* out   = (float*)d_out;
  float* outRe = out;
  float* outR  = out + (size_t)NE * 512;
  float* outS  = outR + (size_t)3 * NE;
  float* outM  = outS + (size_t)3 * NE;

  weight_prep<<<dim3(256, 12), 256, 0, stream>>>(W0, W1, W2, SW0, SW1, SW2,
                                                 W0t, W1t, W2t, SW0t, SW1t, SW2b);
  relu_cvt_x<<<dim3(NE * 64 / 4 / 256), 256, 0, stream>>>((const float4*)x,
                                                          (ushort4*)Xb);
  build_idx<<<dim3(nchunks, 3), 256, 0, stream>>>(y, prs, (int)chunk,
                                                  idxL, posA, cnts);

  for (int c = 0; c < nchunks; ++c) {
    const long r0 = (long)c * chunk;
    // trunk: Xb -> T0 -> T1 -> (repr fp32, bufR bf16)
    gemmT<<<dim3(chunk / 128, 2, 1), 512, 0, stream>>>(
        Xb + r0 * 64, 0, W0t, 0, b0, 0, nullptr, T0, 0, 64, 512,
        nullptr, 0, nullptr, 0, 0, nullptr, 0, nullptr);
    gemmT<<<dim3(chunk / 128, 2, 1), 512, 0, stream>>>(
        T0, 0, W1t, 0, b1, 0, nullptr, T1, 0, 512, 512,
        nullptr, 0, nullptr, 0, 0, nullptr, 0, nullptr);
    gemmT<<<dim3(chunk / 128, 2, 1), 512, 0, stream>>>(
        T1, 0, W2t, 0, b2, 0, outRe + r0 * 512, bufR, 0, 512, 512,
        nullptr, 0, nullptr, 0, 0, nullptr, 0, nullptr);
    // SW0 batched over p, compacted rows: bufR -> H3[p]
    gemmT<<<dim3(chunk / 128, 2, 3), 512, 0, stream>>>(
        bufR, 0, SW0t, (long)512 * 512, Sb0, 512, nullptr,
        H3, (long)chunk * 512, 512, 512,
        nullptr, 0, nullptr, 0, 0, idxL + r0, NE, cnts + c * 3);
    // SW1 + full fused head on compact rows (Nc=256, y=1)
    gemmT<<<dim3(chunk / 128, 1, 3), 512, 0, stream>>>(
        H3, (long)chunk * 512, SW1t, (long)256 * 512, Sb1, 256, nullptr,
        nullptr, 0, 512, 256,
        SW2b, 256, PB, (long)NE, (int)r0, nullptr, 0, cnts + c * 3);
  }
  head_final<<<dim3(NE / 256, 3), 256, 0, stream>>>(PB, posA, Sb2,
                                                    outR, outS, outM);
}